// Round 3
// baseline (16962.431 us; speedup 1.0000x reference)
//
#include <hip/hip_runtime.h>
#include <hip/hip_bf16.h>
#include <math.h>

using bf16 = __hip_bfloat16;
typedef __bf16 bf16x8 __attribute__((ext_vector_type(8)));
typedef float f32x4 __attribute__((ext_vector_type(4)));

#define B2F(x) __bfloat162float(x)
#define F2B(x) __float2bfloat16(x)

__device__ inline short f2bs(float x) { bf16 b = F2B(x); return *(short*)&b; }

// Problem constants: B=8, L=2048, H=512, D_INNER=1024, NH=16, P=64, N=64
static constexpr int D_PROJ = 2192, CONV_DIM = 1152;

// Workspace layout (bytes). Peak ~122 MB (y_f lives in d_out).
static constexpr size_t SZ_H    = (size_t)16384 * 512 * 2;    // 16.8 MB
static constexpr size_t SZ_ZX   = (size_t)16384 * 2192 * 2;   // 71.8 MB
static constexpr size_t SZ_Y    = (size_t)16384 * 1024 * 2;   // 33.6 MB
static constexpr size_t OFF_H    = 0;
static constexpr size_t OFF_ZX   = OFF_H + SZ_H;
static constexpr size_t OFF_YB   = OFF_ZX + SZ_ZX;
static constexpr size_t OFF_GIDX = OFF_YB + SZ_Y;             // 16384 ints
static constexpr size_t OFF_POOL = OFF_GIDX + 16384 * 4;      // 8*1024 f32

// ---------------------------------------------------------------------------
// MFMA bf16 GEMM: C[M,N] = A[M,K] @ W[N,K]^T + bias
// A: f32 (AF32) or bf16 workspace; W,bias: f32 (converted to bf16 in regs);
// C: bf16 workspace or f32 (CF32, final output).
// 128x128 tile, BK=32, 256 threads (4 waves, each 64x64 = 4x4 mfma tiles)
// ---------------------------------------------------------------------------
template<bool AF32, bool CF32>
__global__ __launch_bounds__(256, 2)
void k_gemm(const void* __restrict__ Ap, const int* __restrict__ gatherIdx,
            const float* __restrict__ W, const float* __restrict__ bias,
            void* __restrict__ Cp, int M, int N, int K, int ldc, int coff)
{
    __shared__ __align__(16) short As[128 * 40]; // pad stride 40 shorts (80B)
    __shared__ __align__(16) short Bs[128 * 40];

    const int tid  = threadIdx.x;
    const int m0   = blockIdx.y * 128;
    const int n0   = blockIdx.x * 128;
    const int wave = tid >> 6, lane = tid & 63;
    const int l15  = lane & 15, quad = lane >> 4;
    const int wm   = (wave & 1) * 64, wn = (wave >> 1) * 64;

    f32x4 acc[4][4];
#pragma unroll
    for (int i = 0; i < 4; ++i)
#pragma unroll
        for (int j = 0; j < 4; ++j) acc[i][j] = f32x4{0.f, 0.f, 0.f, 0.f};

    const int srow = tid >> 2;        // 0..63
    const int scol = (tid & 3) * 8;   // 0,8,16,24 (elements)

    union V8 { int4 i4; short s[8]; };

    for (int k0 = 0; k0 < K; k0 += 32) {
        V8 av[2], bv[2];
#pragma unroll
        for (int it = 0; it < 2; ++it) {
            int r = srow + it * 64;
            long arow = m0 + r;
            if (gatherIdx) arow = gatherIdx[m0 + r];
            if (AF32) {
                const float* ap = (const float*)Ap + arow * (long)K + k0 + scol;
                float4 f0 = *(const float4*)ap;
                float4 f1 = *(const float4*)(ap + 4);
                av[it].s[0] = f2bs(f0.x); av[it].s[1] = f2bs(f0.y);
                av[it].s[2] = f2bs(f0.z); av[it].s[3] = f2bs(f0.w);
                av[it].s[4] = f2bs(f1.x); av[it].s[5] = f2bs(f1.y);
                av[it].s[6] = f2bs(f1.z); av[it].s[7] = f2bs(f1.w);
            } else {
                av[it].i4 = *(const int4*)((const bf16*)Ap + arow * (long)K + k0 + scol);
            }
            int wr = n0 + r;
            if (wr < N) {
                const float* wp = W + (long)wr * K + k0 + scol;
                float4 f0 = *(const float4*)wp;
                float4 f1 = *(const float4*)(wp + 4);
                bv[it].s[0] = f2bs(f0.x); bv[it].s[1] = f2bs(f0.y);
                bv[it].s[2] = f2bs(f0.z); bv[it].s[3] = f2bs(f0.w);
                bv[it].s[4] = f2bs(f1.x); bv[it].s[5] = f2bs(f1.y);
                bv[it].s[6] = f2bs(f1.z); bv[it].s[7] = f2bs(f1.w);
            } else {
                bv[it].i4 = int4{0, 0, 0, 0};
            }
        }
        __syncthreads();
#pragma unroll
        for (int it = 0; it < 2; ++it) {
            int r = srow + it * 64;
            *(int4*)&As[r * 40 + scol] = av[it].i4;
            *(int4*)&Bs[r * 40 + scol] = bv[it].i4;
        }
        __syncthreads();

        bf16x8 af[4], bfr[4];
#pragma unroll
        for (int i = 0; i < 4; ++i)
            af[i] = *(const bf16x8*)&As[(wm + i * 16 + l15) * 40 + quad * 8];
#pragma unroll
        for (int j = 0; j < 4; ++j)
            bfr[j] = *(const bf16x8*)&Bs[(wn + j * 16 + l15) * 40 + quad * 8];
#pragma unroll
        for (int i = 0; i < 4; ++i)
#pragma unroll
            for (int j = 0; j < 4; ++j)
                acc[i][j] = __builtin_amdgcn_mfma_f32_16x16x32_bf16(af[i], bfr[j], acc[i][j], 0, 0, 0);
    }

    // Epilogue: lane holds D[row=quad*4+r][col=l15] per 16x16 tile
#pragma unroll
    for (int j = 0; j < 4; ++j) {
        int col = n0 + wn + j * 16 + l15;
        if (col >= N) continue;
        float bvv = bias ? bias[col] : 0.f;
#pragma unroll
        for (int i = 0; i < 4; ++i) {
#pragma unroll
            for (int r = 0; r < 4; ++r) {
                int row = m0 + wm + i * 16 + quad * 4 + r;
                float v = acc[i][j][r] + bvv;
                if (CF32) ((float*)Cp)[(long)row * ldc + coff + col] = v;
                else      ((bf16*)Cp)[(long)row * ldc + coff + col] = F2B(v);
            }
        }
    }
}

// ---------------------------------------------------------------------------
// gidx[b*2048+t] = b*2048 + (t<len ? len-1-t : t)   (flip row map)
// ---------------------------------------------------------------------------
__global__ void k_mkidx(const int* __restrict__ lens, int* __restrict__ gidx)
{
    int idx = blockIdx.x * 256 + threadIdx.x;  // 16384
    int b = idx >> 11, t = idx & 2047;
    int len = lens[b];
    gidx[idx] = b * 2048 + ((t < len) ? (len - 1 - t) : t);
}

// ---------------------------------------------------------------------------
// Fused selective scan: conv(k=4)+silu on x/B/C slices of zx, dt=softplus,
// dA=exp(-exp(Alog)*dt), then sequential state recurrence.
// Grid: 256 blocks = 8 b x 16 head x 2 p-half; 256 threads = 32 p x 8 ng.
// ---------------------------------------------------------------------------
__global__ __launch_bounds__(256)
void k_scan(const bf16* __restrict__ zx, const float* __restrict__ convw,
            const float* __restrict__ convb, const float* __restrict__ dtb,
            const float* __restrict__ alog, const float* __restrict__ Dp,
            bf16* __restrict__ y)
{
    const int blk = blockIdx.x;
    const int b = blk >> 5, head = (blk >> 1) & 15, ph = blk & 1;
    const float Dv   = Dp[head];
    const float dtbv = dtb[head];
    const float aA   = expf(alog[head]);

    __shared__ float xs[64][32];
    __shared__ float Bsm[64][64], Csm[64][64];
    __shared__ float ys[64][32];
    __shared__ float dA_s[64], dt_s[64];
    __shared__ float cw[160][4], cb[160];  // 0..31 x-chans, 32..95 B, 96..159 C

    const int tid = threadIdx.x;
    if (tid < 160) {
        int c;
        if (tid < 32)      c = head * 64 + ph * 32 + tid;
        else if (tid < 96) c = 1024 + (tid - 32);
        else               c = 1088 + (tid - 96);
#pragma unroll
        for (int j = 0; j < 4; ++j) cw[tid][j] = convw[c * 4 + j];
        cb[tid] = convb[c];
    }

    const int p = tid >> 3, ng = tid & 7;
    float s[8];
#pragma unroll
    for (int i = 0; i < 8; ++i) s[i] = 0.f;
    const long base = (long)b * 2048;
    __syncthreads();

    for (int t0 = 0; t0 < 2048; t0 += 64) {
        // ---- staging: conv+silu into LDS (x: 2048 elems, B: 4096, C: 4096)
        for (int e = tid; e < 10240; e += 256) {
            int r, ch, slot, col;
            if (e < 2048)      { r = e >> 5;            ch = e & 31; slot = ch;      col = 1024 + head * 64 + ph * 32 + ch; }
            else if (e < 6144) { int e2 = e - 2048; r = e2 >> 6; ch = e2 & 63; slot = 32 + ch; col = 2048 + ch; }
            else               { int e2 = e - 6144; r = e2 >> 6; ch = e2 & 63; slot = 96 + ch; col = 2112 + ch; }
            int tg = t0 + r;
            float acc = cb[slot];
#pragma unroll
            for (int j = 0; j < 4; ++j) {
                int tt = tg - 3 + j;
                if (tt >= 0) acc += cw[slot][j] * B2F(zx[(base + tt) * (long)D_PROJ + col]);
            }
            acc = acc / (1.f + expf(-acc));
            if (e < 2048)      xs[r][ch]  = acc;
            else if (e < 6144) Bsm[r][ch] = acc;
            else               Csm[r][ch] = acc;
        }
        if (tid < 64) {
            int tg = t0 + tid;
            float xr = B2F(zx[(base + tg) * (long)D_PROJ + 2176 + head]) + dtbv;
            float sp = (xr > 20.f) ? xr : log1pf(expf(xr));
            dt_s[tid] = sp;
            dA_s[tid] = expf(-aA * sp);
        }
        __syncthreads();

        // ---- 64 sequential steps
        for (int tt = 0; tt < 64; ++tt) {
            float dA = dA_s[tt], dtt = dt_s[tt];
            float xp = xs[tt][p];
            float tmp = dtt * xp;
            const float4 B0 = *(const float4*)&Bsm[tt][ng * 8];
            const float4 B1 = *(const float4*)&Bsm[tt][ng * 8 + 4];
            const float4 C0 = *(const float4*)&Csm[tt][ng * 8];
            const float4 C1 = *(const float4*)&Csm[tt][ng * 8 + 4];
            float ysum;
            s[0] = s[0] * dA + tmp * B0.x; ysum  = s[0] * C0.x;
            s[1] = s[1] * dA + tmp * B0.y; ysum += s[1] * C0.y;
            s[2] = s[2] * dA + tmp * B0.z; ysum += s[2] * C0.z;
            s[3] = s[3] * dA + tmp * B0.w; ysum += s[3] * C0.w;
            s[4] = s[4] * dA + tmp * B1.x; ysum += s[4] * C1.x;
            s[5] = s[5] * dA + tmp * B1.y; ysum += s[5] * C1.y;
            s[6] = s[6] * dA + tmp * B1.z; ysum += s[6] * C1.z;
            s[7] = s[7] * dA + tmp * B1.w; ysum += s[7] * C1.w;
            ysum += __shfl_xor(ysum, 1);
            ysum += __shfl_xor(ysum, 2);
            ysum += __shfl_xor(ysum, 4);
            if (ng == 0) ys[tt][p] = ysum + Dv * xp;
        }
        __syncthreads();

        // ---- write y tile (2048 elems)
        for (int e = tid; e < 2048; e += 256) {
            int r = e >> 5, ch = e & 31;
            y[(base + t0 + r) * 1024L + head * 64 + ph * 32 + ch] = F2B(ys[r][ch]);
        }
    }
}

// ---------------------------------------------------------------------------
// Gate (y *= silu(z)) + RMSNorm * norm_w, in-place on y. One dir per launch.
// ---------------------------------------------------------------------------
__global__ __launch_bounds__(256)
void k_gate(bf16* __restrict__ yp, const bf16* __restrict__ zxp,
            const float* __restrict__ nw)
{
    long bt = blockIdx.x;              // 0..16383
    bf16* y = yp + bt * 1024;
    const bf16* z = zxp + bt * (long)D_PROJ;
    int tid = threadIdx.x;
    float g[4], ss = 0.f;
#pragma unroll
    for (int i = 0; i < 4; ++i) {
        int c = tid * 4 + i;
        float zz = B2F(z[c]);
        float yy = B2F(y[c]);
        float gg = yy * (zz / (1.f + expf(-zz)));
        g[i] = gg; ss += gg * gg;
    }
#pragma unroll
    for (int o = 1; o < 64; o <<= 1) ss += __shfl_xor(ss, o);
    __shared__ float red[4];
    if ((tid & 63) == 0) red[tid >> 6] = ss;
    __syncthreads();
    float tot = red[0] + red[1] + red[2] + red[3];
    float sc = rsqrtf(tot * (1.f / 1024.f) + 1e-5f);
#pragma unroll
    for (int i = 0; i < 4; ++i) {
        int c = tid * 4 + i;
        y[c] = F2B(g[i] * sc * nw[c]);
    }
}

// in-place flip via swaps: rows of 1024 bf16 (128 int4)
__global__ void k_swap(bf16* __restrict__ buf, const int* __restrict__ lens)
{
    int idx = blockIdx.x * 256 + threadIdx.x;  // 8*1024*128
    int v = idx & 127;
    int r = idx >> 7;
    int b = r >> 10, t = r & 1023;
    int len = lens[b];
    int t2 = len - 1 - t;
    if (t < len && t < t2) {
        int4* p = (int4*)buf;
        long i1 = ((long)b * 2048 + t)  * 128 + v;
        long i2 = ((long)b * 2048 + t2) * 128 + v;
        int4 a = p[i1], c = p[i2];
        p[i1] = c; p[i2] = a;
    }
}

// LayerNorm(out + h) * g + b -> h (in place). One block per token row (512).
__global__ __launch_bounds__(256)
void k_ln(const bf16* __restrict__ outb, bf16* __restrict__ h,
          const float* __restrict__ g, const float* __restrict__ bb)
{
    long r = (long)blockIdx.x * 512;
    int tid = threadIdx.x;
    float v0 = B2F(outb[r + tid])       + B2F(h[r + tid]);
    float v1 = B2F(outb[r + tid + 256]) + B2F(h[r + tid + 256]);
    __shared__ float red[4], red2[4];
    float s = v0 + v1;
#pragma unroll
    for (int o = 1; o < 64; o <<= 1) s += __shfl_xor(s, o);
    if ((tid & 63) == 0) red[tid >> 6] = s;
    __syncthreads();
    float mu = (red[0] + red[1] + red[2] + red[3]) * (1.f / 512.f);
    float d0 = v0 - mu, d1 = v1 - mu;
    float q = d0 * d0 + d1 * d1;
#pragma unroll
    for (int o = 1; o < 64; o <<= 1) q += __shfl_xor(q, o);
    if ((tid & 63) == 0) red2[tid >> 6] = q;
    __syncthreads();
    float var = (red2[0] + red2[1] + red2[2] + red2[3]) * (1.f / 512.f);
    float rs = rsqrtf(var + 1e-5f);
    h[r + tid]       = F2B(d0 * rs * g[tid]       + bb[tid]);
    h[r + tid + 256] = F2B(d1 * rs * g[tid + 256] + bb[tid + 256]);
}

// masked-sum pooling partials: atomicAdd into pooled[8][1024] (f32)
__global__ void k_pool(const float* __restrict__ enc, const int* __restrict__ lens,
                       float* __restrict__ pooled)
{
    int bid = blockIdx.x;             // 512 = 8 b * 4 cgrp * 16 tchunk
    int b = bid >> 6;
    int cg = (bid >> 4) & 3, tc = bid & 15;
    int c = cg * 256 + threadIdx.x;
    int len = lens[b];
    float s = 0.f;
    int tend = tc * 128 + 128;
    for (int t = tc * 128; t < tend; ++t)
        if (t < len) s += enc[((long)b * 2048 + t) * 1024 + c];
    atomicAdd(&pooled[b * 1024 + c], s);
}

// encoder_hidden = tanh(pooled/len @ W_ad^T + b_ad)
__global__ void k_adapter(const float* __restrict__ pooled, const float* __restrict__ Wad,
                          const float* __restrict__ bad, const int* __restrict__ lens,
                          float* __restrict__ outh)
{
    int idx = blockIdx.x * 256 + threadIdx.x;  // 4096
    int b = idx >> 9, j = idx & 511;
    const float* wrow = Wad + (long)j * 1024;
    const float* prow = pooled + b * 1024;
    float acc = 0.f;
    for (int k = 0; k < 1024; ++k) acc += prow[k] * wrow[k];
    int li = lens[b]; if (li < 1) li = 1;
    acc = acc / (float)li + bad[j];
    outh[idx] = tanhf(acc);
}

// ---------------------------------------------------------------------------
static void gemm(const void* A, bool af32, const int* gather, const float* W,
                 const float* bias, void* C, bool cf32,
                 int M, int N, int K, int ldc, int coff, hipStream_t s)
{
    dim3 grid((N + 127) / 128, M / 128);
    if (af32) {
        if (cf32) k_gemm<true,  true ><<<grid, 256, 0, s>>>(A, gather, W, bias, C, M, N, K, ldc, coff);
        else      k_gemm<true,  false><<<grid, 256, 0, s>>>(A, gather, W, bias, C, M, N, K, ldc, coff);
    } else {
        if (cf32) k_gemm<false, true ><<<grid, 256, 0, s>>>(A, gather, W, bias, C, M, N, K, ldc, coff);
        else      k_gemm<false, false><<<grid, 256, 0, s>>>(A, gather, W, bias, C, M, N, K, ldc, coff);
    }
}

extern "C" void kernel_launch(void* const* d_in, const int* in_sizes, int n_in,
                              void* d_out, int out_size, void* d_ws, size_t ws_size,
                              hipStream_t stream)
{
    const int*   tok    = (const int*)d_in[0];
    const int*   lens   = (const int*)d_in[1];
    const float* emb    = (const float*)d_in[2];
    const float* W_inp  = (const float*)d_in[3];
    const float* b_inp  = (const float*)d_in[4];
    const float* m_Win  = (const float*)d_in[5];
    const float* m_convw= (const float*)d_in[6];
    const float* m_convb= (const float*)d_in[7];
    const float* m_dtb  = (const float*)d_in[8];
    const float* m_Alog = (const float*)d_in[9];
    const float* m_D    = (const float*)d_in[10];
    const float* m_norm = (const float*)d_in[11];
    const float* m_Wout = (const float*)d_in[12];
    const float* blk_Wo = (const float*)d_in[13];
    const float* blk_bo = (const float*)d_in[14];
    const float* ln_g   = (const float*)d_in[15];
    const float* ln_b   = (const float*)d_in[16];
    const float* W_enc  = (const float*)d_in[17];
    const float* b_enc  = (const float*)d_in[18];
    const float* W_ad   = (const float*)d_in[19];
    const float* b_ad   = (const float*)d_in[20];

    char* ws = (char*)d_ws;
    bf16* h      = (bf16*)(ws + OFF_H);
    bf16* zx     = (bf16*)(ws + OFF_ZX);
    bf16* y_b    = (bf16*)(ws + OFF_YB);
    int*  gidx   = (int*)(ws + OFF_GIDX);
    float* pooled= (float*)(ws + OFF_POOL);
    float* dout  = (float*)d_out;
    bf16* y_f    = (bf16*)d_out;            // d_out doubles as y_f scratch (dead before final gemm)
    bf16* comb   = (bf16*)(ws + OFF_ZX);    // alias zx (dead after gate b)
    bf16* outbuf = (bf16*)(ws + OFF_YB);    // alias y_b (dead after outproj b)

    // flip row map (lens constant across layers)
    k_mkidx<<<64, 256, 0, stream>>>(lens, gidx);

    // h = emb[tok] @ W_inp^T + b_inp
    gemm(emb, true, tok, W_inp, b_inp, h, false, 16384, 512, 512, 512, 0, stream);

    for (int l = 0; l < 4; ++l) {
        const float* Wi_f = m_Win  + (size_t)(l * 2 + 0) * D_PROJ * 512;
        const float* Wi_b = m_Win  + (size_t)(l * 2 + 1) * D_PROJ * 512;
        const float* cw_f = m_convw + (size_t)(l * 2 + 0) * CONV_DIM * 4;
        const float* cw_b = m_convw + (size_t)(l * 2 + 1) * CONV_DIM * 4;
        const float* cb_f = m_convb + (size_t)(l * 2 + 0) * CONV_DIM;
        const float* cb_b = m_convb + (size_t)(l * 2 + 1) * CONV_DIM;

        // ---- forward dir: inproj -> scan -> gate  (y_f in d_out)
        gemm(h, false, nullptr, Wi_f, nullptr, zx, false, 16384, D_PROJ, 512, D_PROJ, 0, stream);
        k_scan<<<256, 256, 0, stream>>>(zx, cw_f, cb_f, m_dtb + l * 32, m_Alog + l * 32,
                                        m_D + l * 32, y_f);
        k_gate<<<16384, 256, 0, stream>>>(y_f, zx, m_norm + (size_t)(l * 2) * 1024);

        // ---- backward dir: inproj(gathered rows of h) -> scan -> gate -> unflip
        gemm(h, false, gidx, Wi_b, nullptr, zx, false, 16384, D_PROJ, 512, D_PROJ, 0, stream);
        k_scan<<<256, 256, 0, stream>>>(zx, cw_b, cb_b, m_dtb + l * 32 + 16,
                                        m_Alog + l * 32 + 16, m_D + l * 32 + 16, y_b);
        k_gate<<<16384, 256, 0, stream>>>(y_b, zx, m_norm + (size_t)(l * 2 + 1) * 1024);
        k_swap<<<4096, 256, 0, stream>>>(y_b, lens);

        // ---- out-projections into comb halves (comb aliases dead zx)
        gemm(y_f, false, nullptr, m_Wout + (size_t)(l * 2 + 0) * 512 * 1024, nullptr, comb,
             false, 16384, 512, 1024, 1024, 0, stream);
        gemm(y_b, false, nullptr, m_Wout + (size_t)(l * 2 + 1) * 512 * 1024, nullptr, comb,
             false, 16384, 512, 1024, 1024, 512, stream);
        // ---- block out-projection (outbuf aliases dead y_b)
        gemm(comb, false, nullptr, blk_Wo + (size_t)l * 512 * 1024, blk_bo + l * 512, outbuf,
             false, 16384, 512, 1024, 512, 0, stream);
        // ---- residual + layernorm -> h
        k_ln<<<16384, 256, 0, stream>>>(outbuf, h, ln_g + l * 512, ln_b + l * 512);
    }

    // encoder_outputs = h @ W_enc^T + b_enc  -> d_out as f32 (y_f dead)
    gemm(h, false, nullptr, W_enc, b_enc, dout, true, 16384, 1024, 512, 1024, 0, stream);

    // pooled mean + adapter
    hipMemsetAsync(pooled, 0, 8 * 1024 * sizeof(float), stream);
    k_pool<<<512, 256, 0, stream>>>(dout, lens, pooled);
    k_adapter<<<16, 256, 0, stream>>>(pooled, W_ad, b_ad, lens, dout + (size_t)16384 * 1024);
}

// Round 4
// 5888.124 us; speedup vs baseline: 2.8808x; 2.8808x over previous
//
#include <hip/hip_runtime.h>
#include <hip/hip_bf16.h>
#include <math.h>

using bf16 = __hip_bfloat16;
typedef __bf16 bf16x8 __attribute__((ext_vector_type(8)));
typedef float f32x4 __attribute__((ext_vector_type(4)));

#define B2F(x) __bfloat162float(x)
#define F2B(x) __float2bfloat16(x)

__device__ inline short f2bs(float x) { bf16 b = F2B(x); return *(short*)&b; }
__device__ inline float bs2f(short x) { bf16 b; *(short*)&b = x; return B2F(b); }

// Problem constants: B=8, L=2048, H=512, D_INNER=1024, NH=16, P=64, N=64
static constexpr int D_PROJ = 2192, CONV_DIM = 1152;
static constexpr int NCHUNK = 8, CLEN = 256;   // 8 chunks x 256 steps

// Workspace layout (bytes). Total ~146.4 MB. y_f/y_b live in d_out (67.1 MB).
static constexpr size_t OFF_H    = 0;                    // 16384x512  bf16  16.8 MB
static constexpr size_t OFF_ZX   = 16777216;             // 16384x2192 bf16  71.8 MB (comb aliases)
static constexpr size_t OFF_XC   = 88604672;             // 16384x1152 bf16  37.7 MB (outbuf aliases)
static constexpr size_t OFF_S    = 126353408;            // 1024x4096  f32   16.8 MB
static constexpr size_t OFF_PT   = 143130624;            // 16384x16   f32    1.0 MB
static constexpr size_t OFF_PC   = 144179200;            // 1024       f32    4 KB
static constexpr size_t OFF_DTV  = 144183296;            // 16384x16   f32    1.0 MB
static constexpr size_t OFF_DAV  = 145231872;            // 16384x16   f32    1.0 MB
static constexpr size_t OFF_GIDX = 146280448;            // 16384      i32
static constexpr size_t OFF_POOL = 146345984;            // 8x1024     f32

// ---------------------------------------------------------------------------
// MFMA bf16 GEMM: C[M,N] = A[M,K] @ W[N,K]^T + bias   (unchanged from R3)
// ---------------------------------------------------------------------------
template<bool AF32, bool CF32>
__global__ __launch_bounds__(256, 2)
void k_gemm(const void* __restrict__ Ap, const int* __restrict__ gatherIdx,
            const float* __restrict__ W, const float* __restrict__ bias,
            void* __restrict__ Cp, int M, int N, int K, int ldc, int coff)
{
    __shared__ __align__(16) short As[128 * 40];
    __shared__ __align__(16) short Bs[128 * 40];

    const int tid  = threadIdx.x;
    const int m0   = blockIdx.y * 128;
    const int n0   = blockIdx.x * 128;
    const int wave = tid >> 6, lane = tid & 63;
    const int l15  = lane & 15, quad = lane >> 4;
    const int wm   = (wave & 1) * 64, wn = (wave >> 1) * 64;

    f32x4 acc[4][4];
#pragma unroll
    for (int i = 0; i < 4; ++i)
#pragma unroll
        for (int j = 0; j < 4; ++j) acc[i][j] = f32x4{0.f, 0.f, 0.f, 0.f};

    const int srow = tid >> 2;
    const int scol = (tid & 3) * 8;

    union V8 { int4 i4; short s[8]; };

    for (int k0 = 0; k0 < K; k0 += 32) {
        V8 av[2], bv[2];
#pragma unroll
        for (int it = 0; it < 2; ++it) {
            int r = srow + it * 64;
            long arow = m0 + r;
            if (gatherIdx) arow = gatherIdx[m0 + r];
            if (AF32) {
                const float* ap = (const float*)Ap + arow * (long)K + k0 + scol;
                float4 f0 = *(const float4*)ap;
                float4 f1 = *(const float4*)(ap + 4);
                av[it].s[0] = f2bs(f0.x); av[it].s[1] = f2bs(f0.y);
                av[it].s[2] = f2bs(f0.z); av[it].s[3] = f2bs(f0.w);
                av[it].s[4] = f2bs(f1.x); av[it].s[5] = f2bs(f1.y);
                av[it].s[6] = f2bs(f1.z); av[it].s[7] = f2bs(f1.w);
            } else {
                av[it].i4 = *(const int4*)((const bf16*)Ap + arow * (long)K + k0 + scol);
            }
            int wr = n0 + r;
            if (wr < N) {
                const float* wp = W + (long)wr * K + k0 + scol;
                float4 f0 = *(const float4*)wp;
                float4 f1 = *(const float4*)(wp + 4);
                bv[it].s[0] = f2bs(f0.x); bv[it].s[1] = f2bs(f0.y);
                bv[it].s[2] = f2bs(f0.z); bv[it].s[3] = f2bs(f0.w);
                bv[it].s[4] = f2bs(f1.x); bv[it].s[5] = f2bs(f1.y);
                bv[it].s[6] = f2bs(f1.z); bv[it].s[7] = f2bs(f1.w);
            } else {
                bv[it].i4 = int4{0, 0, 0, 0};
            }
        }
        __syncthreads();
#pragma unroll
        for (int it = 0; it < 2; ++it) {
            int r = srow + it * 64;
            *(int4*)&As[r * 40 + scol] = av[it].i4;
            *(int4*)&Bs[r * 40 + scol] = bv[it].i4;
        }
        __syncthreads();

        bf16x8 af[4], bfr[4];
#pragma unroll
        for (int i = 0; i < 4; ++i)
            af[i] = *(const bf16x8*)&As[(wm + i * 16 + l15) * 40 + quad * 8];
#pragma unroll
        for (int j = 0; j < 4; ++j)
            bfr[j] = *(const bf16x8*)&Bs[(wn + j * 16 + l15) * 40 + quad * 8];
#pragma unroll
        for (int i = 0; i < 4; ++i)
#pragma unroll
            for (int j = 0; j < 4; ++j)
                acc[i][j] = __builtin_amdgcn_mfma_f32_16x16x32_bf16(af[i], bfr[j], acc[i][j], 0, 0, 0);
    }

#pragma unroll
    for (int j = 0; j < 4; ++j) {
        int col = n0 + wn + j * 16 + l15;
        if (col >= N) continue;
        float bvv = bias ? bias[col] : 0.f;
#pragma unroll
        for (int i = 0; i < 4; ++i) {
#pragma unroll
            for (int r = 0; r < 4; ++r) {
                int row = m0 + wm + i * 16 + quad * 4 + r;
                float v = acc[i][j][r] + bvv;
                if (CF32) ((float*)Cp)[(long)row * ldc + coff + col] = v;
                else      ((bf16*)Cp)[(long)row * ldc + coff + col] = F2B(v);
            }
        }
    }
}

// ---------------------------------------------------------------------------
// flip row map
// ---------------------------------------------------------------------------
__global__ void k_mkidx(const int* __restrict__ lens, int* __restrict__ gidx)
{
    int idx = blockIdx.x * 256 + threadIdx.x;  // 16384
    int b = idx >> 11, t = idx & 2047;
    int len = lens[b];
    gidx[idx] = b * 2048 + ((t < len) ? (len - 1 - t) : t);
}

// ---------------------------------------------------------------------------
// Depthwise causal conv(k=4)+bias+silu: zx[:,1024:2176] -> xc[16384][1152] bf16
// One thread = 8 channels of one row. Coalesced int4 loads/stores.
// ---------------------------------------------------------------------------
__global__ __launch_bounds__(256)
void k_conv(const bf16* __restrict__ zx, const float* __restrict__ w,
            const float* __restrict__ cb, bf16* __restrict__ xc)
{
    long idx = (long)blockIdx.x * 256 + threadIdx.x;   // 16384*144
    if (idx >= 16384L * 144) return;
    int  c8 = (int)(idx % 144);
    long bt = idx / 144;
    int  t  = (int)(bt & 2047);
    int  c0 = c8 * 8;

    float acc[8];
#pragma unroll
    for (int i = 0; i < 8; ++i) acc[i] = cb[c0 + i];
#pragma unroll
    for (int j = 0; j < 4; ++j) {
        if (t >= 3 - j) {
            bf16x8 v = *(const bf16x8*)&zx[(bt - 3 + j) * (long)D_PROJ + 1024 + c0];
#pragma unroll
            for (int i = 0; i < 8; ++i) acc[i] += w[(c0 + i) * 4 + j] * (float)v[i];
        }
    }
    short out[8];
#pragma unroll
    for (int i = 0; i < 8; ++i) {
        float a = acc[i];
        out[i] = f2bs(a / (1.f + expf(-a)));
    }
    *(int4*)&xc[bt * (long)CONV_DIM + c0] = *(int4*)out;
}

// ---------------------------------------------------------------------------
// dt = softplus(raw + bias); dA = exp(-exp(Alog)*dt). One dir per launch.
// ---------------------------------------------------------------------------
__global__ void k_dt(const bf16* __restrict__ zx, const float* __restrict__ dtb,
                     const float* __restrict__ alog,
                     float* __restrict__ dtv, float* __restrict__ dAv)
{
    int idx = blockIdx.x * 256 + threadIdx.x;   // 16384*16
    int hh = idx & 15;
    long bt = idx >> 4;
    float x  = B2F(zx[bt * (long)D_PROJ + 2176 + hh]) + dtb[hh];
    float sp = (x > 20.f) ? x : log1pf(expf(x));
    dtv[idx] = sp;
    dAv[idx] = expf(-expf(alog[hh]) * sp);
}

// ---------------------------------------------------------------------------
// Inclusive cumprod of dA within each chunk -> Pt; chunk totals -> Pc.
// Grid: 1024 blocks = (b*16+h)*8+c, 256 threads (one t each).
// ---------------------------------------------------------------------------
__global__ __launch_bounds__(256)
void k_cum(const float* __restrict__ dAv, float* __restrict__ Pt,
           float* __restrict__ Pc)
{
    int blk = blockIdx.x;
    int c = blk & 7, h = (blk >> 3) & 15, b = blk >> 7;
    int tid = threadIdx.x;
    int t = c * CLEN + tid;
    long gi = ((long)(b * 2048 + t) << 4) + h;
    float v = dAv[gi];
    __shared__ float sa[256], sb[256];
    sa[tid] = v; __syncthreads();
    float* src = sa; float* dst = sb;
    for (int off = 1; off < 256; off <<= 1) {
        float x = src[tid];
        if (tid >= off) x *= src[tid - off];
        dst[tid] = x;
        __syncthreads();
        float* tp = src; src = dst; dst = tp;
    }
    float incl = src[tid];
    Pt[gi] = incl;
    if (tid == 255) Pc[blk] = incl;
}

// ---------------------------------------------------------------------------
// Phase 1: local scan per chunk (zero init). Writes y_local and final state.
// Grid: 1024 = ((b*16+h)*8+c). 256 threads: p=tid>>2 (0..63), ng=tid&3 (16 n).
// LDS ~48.5 KB -> 3 blocks/CU.
// ---------------------------------------------------------------------------
__global__ __launch_bounds__(256)
void k_ph1(const bf16* __restrict__ xc, const float* __restrict__ dtv,
           const float* __restrict__ dAv, const float* __restrict__ Dp,
           bf16* __restrict__ y, float* __restrict__ Sl)
{
    const int blk = blockIdx.x;
    const int c = blk & 7, h = (blk >> 3) & 15, b = blk >> 7;
    const float Dv = Dp[h];

    __shared__ __align__(16) short xs[64][64];        // bf16
    __shared__ __align__(16) float Bsm[64][64], Csm[64][64];
    __shared__ __align__(16) short ysb[64][64];       // bf16
    __shared__ float dA_s[64], dt_s[64];

    const int tid = threadIdx.x;
    const int p = tid >> 2, ng = tid & 3;
    float s[16];
#pragma unroll
    for (int i = 0; i < 16; ++i) s[i] = 0.f;
    const long base = (long)b * 2048;
    const int tcs = c * CLEN;

    for (int tile = 0; tile < 4; ++tile) {
        const int t0 = tcs + tile * 64;
        // ---- stage x (bf16 copy), B/C (bf16 -> f32)
        for (int i = tid; i < 512; i += 256) {
            int r = i >> 3, sg = (i & 7) * 8;
            *(int4*)&xs[r][sg] = *(const int4*)&xc[(base + t0 + r) * (long)CONV_DIM + h * 64 + sg];
        }
        for (int i = tid; i < 512; i += 256) {
            int r = i >> 3, sg = (i & 7) * 8;
            bf16x8 v = *(const bf16x8*)&xc[(base + t0 + r) * (long)CONV_DIM + 1024 + sg];
#pragma unroll
            for (int j = 0; j < 8; ++j) Bsm[r][sg + j] = (float)v[j];
        }
        for (int i = tid; i < 512; i += 256) {
            int r = i >> 3, sg = (i & 7) * 8;
            bf16x8 v = *(const bf16x8*)&xc[(base + t0 + r) * (long)CONV_DIM + 1088 + sg];
#pragma unroll
            for (int j = 0; j < 8; ++j) Csm[r][sg + j] = (float)v[j];
        }
        if (tid < 64) {
            long gi = ((base + t0 + tid) << 4) + h;
            dA_s[tid] = dAv[gi];
            dt_s[tid] = dtv[gi];
        }
        __syncthreads();

        // ---- 64 sequential steps
#pragma unroll 4
        for (int tt = 0; tt < 64; ++tt) {
            float dA = dA_s[tt], dtt = dt_s[tt];
            float xp = bs2f(xs[tt][p]);
            float tmp = dtt * xp;
            const float4* Bp = (const float4*)&Bsm[tt][ng * 16];
            const float4* Cp = (const float4*)&Csm[tt][ng * 16];
            float ysum = 0.f;
#pragma unroll
            for (int q = 0; q < 4; ++q) {
                float4 Bv = Bp[q], Cv = Cp[q];
                s[q*4+0] = s[q*4+0] * dA + tmp * Bv.x; ysum += s[q*4+0] * Cv.x;
                s[q*4+1] = s[q*4+1] * dA + tmp * Bv.y; ysum += s[q*4+1] * Cv.y;
                s[q*4+2] = s[q*4+2] * dA + tmp * Bv.z; ysum += s[q*4+2] * Cv.z;
                s[q*4+3] = s[q*4+3] * dA + tmp * Bv.w; ysum += s[q*4+3] * Cv.w;
            }
            ysum += __shfl_xor(ysum, 1);
            ysum += __shfl_xor(ysum, 2);
            if (ng == 0) ysb[tt][p] = f2bs(ysum + Dv * xp);
        }
        __syncthreads();

        // ---- write y tile (coalesced ushort4)
        for (int i = tid; i < 1024; i += 256) {
            int r = i >> 4, c4 = (i & 15) * 4;
            *(ushort4*)&y[(base + t0 + r) * 1024L + h * 64 + c4] = *(ushort4*)&ysb[r][c4];
        }
    }

    // final local state
    float* Sp = Sl + (long)blk * 4096 + p * 64 + ng * 16;
#pragma unroll
    for (int q = 0; q < 4; ++q)
        *(float4*)&Sp[q * 4] = float4{s[q*4+0], s[q*4+1], s[q*4+2], s[q*4+3]};
}

// ---------------------------------------------------------------------------
// Phase 2: sequential combine of chunk states. 128 blocks (b*16+h), 256 thr.
// Slocal[c] is overwritten with Sinit[c] (state at chunk start).
// ---------------------------------------------------------------------------
__global__ __launch_bounds__(256)
void k_comb(float* __restrict__ Sl, const float* __restrict__ Pc)
{
    int bh = blockIdx.x;
    int tid = threadIdx.x;
    float run[16];
#pragma unroll
    for (int i = 0; i < 16; ++i) run[i] = 0.f;
    for (int c = 0; c < NCHUNK; ++c) {
        float* ptr = Sl + ((long)(bh * NCHUNK + c)) * 4096 + tid * 16;
        float pc = Pc[bh * NCHUNK + c];
#pragma unroll
        for (int q = 0; q < 4; ++q) {
            float4 v = *(float4*)&ptr[q * 4];
            float4 init = float4{run[q*4+0], run[q*4+1], run[q*4+2], run[q*4+3]};
            run[q*4+0] = v.x + pc * run[q*4+0];
            run[q*4+1] = v.y + pc * run[q*4+1];
            run[q*4+2] = v.z + pc * run[q*4+2];
            run[q*4+3] = v.w + pc * run[q*4+3];
            *(float4*)&ptr[q * 4] = init;
        }
    }
}

// ---------------------------------------------------------------------------
// Phase 3: y[t] += Pt[t] * (C_t · Sinit). Grid 1024, 256 threads.
// ---------------------------------------------------------------------------
__global__ __launch_bounds__(256)
void k_ph3(const float* __restrict__ Sl, const bf16* __restrict__ xc,
           const float* __restrict__ Pt, bf16* __restrict__ y)
{
    const int blk = blockIdx.x;
    const int c = blk & 7, h = (blk >> 3) & 15, b = blk >> 7;
    if (c == 0) return;   // Sinit = 0

    __shared__ __align__(16) float Cs[64][64];
    __shared__ __align__(16) short ysb[64][64];
    __shared__ float Pts[64];

    const int tid = threadIdx.x;
    const int p = tid >> 2, ng = tid & 3;
    const long base = (long)b * 2048;
    const int tcs = c * CLEN;

    float Sv[16];
    const float* Sp = Sl + (long)blk * 4096 + p * 64 + ng * 16;
#pragma unroll
    for (int q = 0; q < 4; ++q) {
        float4 v = *(const float4*)&Sp[q * 4];
        Sv[q*4+0] = v.x; Sv[q*4+1] = v.y; Sv[q*4+2] = v.z; Sv[q*4+3] = v.w;
    }

    for (int tile = 0; tile < 4; ++tile) {
        const int t0 = tcs + tile * 64;
        for (int i = tid; i < 512; i += 256) {
            int r = i >> 3, sg = (i & 7) * 8;
            bf16x8 v = *(const bf16x8*)&xc[(base + t0 + r) * (long)CONV_DIM + 1088 + sg];
#pragma unroll
            for (int j = 0; j < 8; ++j) Cs[r][sg + j] = (float)v[j];
        }
        if (tid < 64) Pts[tid] = Pt[((base + t0 + tid) << 4) + h];
        __syncthreads();

#pragma unroll 4
        for (int tt = 0; tt < 64; ++tt) {
            const float4* Cp = (const float4*)&Cs[tt][ng * 16];
            float dot = 0.f;
#pragma unroll
            for (int q = 0; q < 4; ++q) {
                float4 Cv = Cp[q];
                dot += Sv[q*4+0] * Cv.x + Sv[q*4+1] * Cv.y
                     + Sv[q*4+2] * Cv.z + Sv[q*4+3] * Cv.w;
            }
            dot += __shfl_xor(dot, 1);
            dot += __shfl_xor(dot, 2);
            if (ng == 0) ysb[tt][p] = f2bs(Pts[tt] * dot);
        }
        __syncthreads();

        // RMW y tile
        for (int i = tid; i < 1024; i += 256) {
            int r = i >> 4, c4 = (i & 15) * 4;
            bf16* yp = &y[(base + t0 + r) * 1024L + h * 64 + c4];
            ushort4 old = *(ushort4*)yp;
            short* corr = &ysb[r][c4];
            ushort4 nw;
            nw.x = (unsigned short)f2bs(bs2f((short)old.x) + bs2f(corr[0]));
            nw.y = (unsigned short)f2bs(bs2f((short)old.y) + bs2f(corr[1]));
            nw.z = (unsigned short)f2bs(bs2f((short)old.z) + bs2f(corr[2]));
            nw.w = (unsigned short)f2bs(bs2f((short)old.w) + bs2f(corr[3]));
            *(ushort4*)yp = nw;
        }
        __syncthreads();
    }
}

// ---------------------------------------------------------------------------
// Gate (y *= silu(z)) + RMSNorm * norm_w, in-place on y.
// ---------------------------------------------------------------------------
__global__ __launch_bounds__(256)
void k_gate(bf16* __restrict__ yp, const bf16* __restrict__ zxp,
            const float* __restrict__ nw)
{
    long bt = blockIdx.x;
    bf16* y = yp + bt * 1024;
    const bf16* z = zxp + bt * (long)D_PROJ;
    int tid = threadIdx.x;
    float g[4], ss = 0.f;
#pragma unroll
    for (int i = 0; i < 4; ++i) {
        int c = tid * 4 + i;
        float zz = B2F(z[c]);
        float yy = B2F(y[c]);
        float gg = yy * (zz / (1.f + expf(-zz)));
        g[i] = gg; ss += gg * gg;
    }
#pragma unroll
    for (int o = 1; o < 64; o <<= 1) ss += __shfl_xor(ss, o);
    __shared__ float red[4];
    if ((tid & 63) == 0) red[tid >> 6] = ss;
    __syncthreads();
    float tot = red[0] + red[1] + red[2] + red[3];
    float sc = rsqrtf(tot * (1.f / 1024.f) + 1e-5f);
#pragma unroll
    for (int i = 0; i < 4; ++i) {
        int c = tid * 4 + i;
        y[c] = F2B(g[i] * sc * nw[c]);
    }
}

// in-place flip via swaps: rows of 1024 bf16 (128 int4)
__global__ void k_swap(bf16* __restrict__ buf, const int* __restrict__ lens)
{
    int idx = blockIdx.x * 256 + threadIdx.x;
    int v = idx & 127;
    int r = idx >> 7;
    int b = r >> 10, t = r & 1023;
    int len = lens[b];
    int t2 = len - 1 - t;
    if (t < len && t < t2) {
        int4* p = (int4*)buf;
        long i1 = ((long)b * 2048 + t)  * 128 + v;
        long i2 = ((long)b * 2048 + t2) * 128 + v;
        int4 a = p[i1], c = p[i2];
        p[i1] = c; p[i2] = a;
    }
}

// LayerNorm(out + h) * g + b -> h (in place)
__global__ __launch_bounds__(256)
void k_ln(const bf16* __restrict__ outb, bf16* __restrict__ h,
          const float* __restrict__ g, const float* __restrict__ bb)
{
    long r = (long)blockIdx.x * 512;
    int tid = threadIdx.x;
    float v0 = B2F(outb[r + tid])       + B2F(h[r + tid]);
    float v1 = B2F(outb[r + tid + 256]) + B2F(h[r + tid + 256]);
    __shared__ float red[4], red2[4];
    float s = v0 + v1;
#pragma unroll
    for (int o = 1; o < 64; o <<= 1) s += __shfl_xor(s, o);
    if ((tid & 63) == 0) red[tid >> 6] = s;
    __syncthreads();
    float mu = (red[0] + red[1] + red[2] + red[3]) * (1.f / 512.f);
    float d0 = v0 - mu, d1 = v1 - mu;
    float q = d0 * d0 + d1 * d1;
#pragma unroll
    for (int o = 1; o < 64; o <<= 1) q += __shfl_xor(q, o);
    if ((tid & 63) == 0) red2[tid >> 6] = q;
    __syncthreads();
    float var = (red2[0] + red2[1] + red2[2] + red2[3]) * (1.f / 512.f);
    float rs = rsqrtf(var + 1e-5f);
    h[r + tid]       = F2B(d0 * rs * g[tid]       + bb[tid]);
    h[r + tid + 256] = F2B(d1 * rs * g[tid + 256] + bb[tid + 256]);
}

// masked-sum pooling partials
__global__ void k_pool(const float* __restrict__ enc, const int* __restrict__ lens,
                       float* __restrict__ pooled)
{
    int bid = blockIdx.x;
    int b = bid >> 6;
    int cg = (bid >> 4) & 3, tc = bid & 15;
    int c = cg * 256 + threadIdx.x;
    int len = lens[b];
    float s = 0.f;
    int tend = tc * 128 + 128;
    for (int t = tc * 128; t < tend; ++t)
        if (t < len) s += enc[((long)b * 2048 + t) * 1024 + c];
    atomicAdd(&pooled[b * 1024 + c], s);
}

// encoder_hidden = tanh(pooled/len @ W_ad^T + b_ad)
__global__ void k_adapter(const float* __restrict__ pooled, const float* __restrict__ Wad,
                          const float* __restrict__ bad, const int* __restrict__ lens,
                          float* __restrict__ outh)
{
    int idx = blockIdx.x * 256 + threadIdx.x;
    int b = idx >> 9, j = idx & 511;
    const float* wrow = Wad + (long)j * 1024;
    const float* prow = pooled + b * 1024;
    float acc = 0.f;
    for (int k = 0; k < 1024; ++k) acc += prow[k] * wrow[k];
    int li = lens[b]; if (li < 1) li = 1;
    acc = acc / (float)li + bad[j];
    outh[idx] = tanhf(acc);
}

// ---------------------------------------------------------------------------
static void gemm(const void* A, bool af32, const int* gather, const float* W,
                 const float* bias, void* C, bool cf32,
                 int M, int N, int K, int ldc, int coff, hipStream_t s)
{
    dim3 grid((N + 127) / 128, M / 128);
    if (af32) {
        if (cf32) k_gemm<true,  true ><<<grid, 256, 0, s>>>(A, gather, W, bias, C, M, N, K, ldc, coff);
        else      k_gemm<true,  false><<<grid, 256, 0, s>>>(A, gather, W, bias, C, M, N, K, ldc, coff);
    } else {
        if (cf32) k_gemm<false, true ><<<grid, 256, 0, s>>>(A, gather, W, bias, C, M, N, K, ldc, coff);
        else      k_gemm<false, false><<<grid, 256, 0, s>>>(A, gather, W, bias, C, M, N, K, ldc, coff);
    }
}

extern "C" void kernel_launch(void* const* d_in, const int* in_sizes, int n_in,
                              void* d_out, int out_size, void* d_ws, size_t ws_size,
                              hipStream_t stream)
{
    const int*   tok    = (const int*)d_in[0];
    const int*   lens   = (const int*)d_in[1];
    const float* emb    = (const float*)d_in[2];
    const float* W_inp  = (const float*)d_in[3];
    const float* b_inp  = (const float*)d_in[4];
    const float* m_Win  = (const float*)d_in[5];
    const float* m_convw= (const float*)d_in[6];
    const float* m_convb= (const float*)d_in[7];
    const float* m_dtb  = (const float*)d_in[8];
    const float* m_Alog = (const float*)d_in[9];
    const float* m_D    = (const float*)d_in[10];
    const float* m_norm = (const float*)d_in[11];
    const float* m_Wout = (const float*)d_in[12];
    const float* blk_Wo = (const float*)d_in[13];
    const float* blk_bo = (const float*)d_in[14];
    const float* ln_g   = (const float*)d_in[15];
    const float* ln_b   = (const float*)d_in[16];
    const float* W_enc  = (const float*)d_in[17];
    const float* b_enc  = (const float*)d_in[18];
    const float* W_ad   = (const float*)d_in[19];
    const float* b_ad   = (const float*)d_in[20];

    char* ws = (char*)d_ws;
    bf16*  h      = (bf16*)(ws + OFF_H);
    bf16*  zx     = (bf16*)(ws + OFF_ZX);
    bf16*  xc     = (bf16*)(ws + OFF_XC);
    float* Sl     = (float*)(ws + OFF_S);
    float* Pt     = (float*)(ws + OFF_PT);
    float* Pc     = (float*)(ws + OFF_PC);
    float* dtv    = (float*)(ws + OFF_DTV);
    float* dAv    = (float*)(ws + OFF_DAV);
    int*   gidx   = (int*)(ws + OFF_GIDX);
    float* pooled = (float*)(ws + OFF_POOL);

    float* dout   = (float*)d_out;
    bf16*  y_f    = (bf16*)d_out;                       // 33.55 MB
    bf16*  y_b    = (bf16*)d_out + (size_t)16384 * 1024; // next 33.55 MB (fits)
    bf16*  comb   = (bf16*)(ws + OFF_ZX);               // alias zx (dead after gates)
    bf16*  outbuf = (bf16*)(ws + OFF_XC);               // alias xc (dead after ph3 bwd)

    k_mkidx<<<64, 256, 0, stream>>>(lens, gidx);

    // h = emb[tok] @ W_inp^T + b_inp
    gemm(emb, true, tok, W_inp, b_inp, h, false, 16384, 512, 512, 512, 0, stream);

    for (int l = 0; l < 4; ++l) {
        for (int dir = 0; dir < 2; ++dir) {
            const float* Wi = m_Win  + (size_t)(l * 2 + dir) * D_PROJ * 512;
            const float* cw = m_convw + (size_t)(l * 2 + dir) * CONV_DIM * 4;
            const float* cbp= m_convb + (size_t)(l * 2 + dir) * CONV_DIM;
            const float* dtb= m_dtb  + l * 32 + dir * 16;
            const float* alg= m_Alog + l * 32 + dir * 16;
            const float* Dpp= m_D    + l * 32 + dir * 16;
            const float* nw = m_norm + (size_t)(l * 2 + dir) * 1024;
            bf16* y = dir ? y_b : y_f;

            gemm(h, false, dir ? gidx : nullptr, Wi, nullptr, zx, false,
                 16384, D_PROJ, 512, D_PROJ, 0, stream);
            k_conv<<<9216, 256, 0, stream>>>(zx, cw, cbp, xc);
            k_dt<<<1024, 256, 0, stream>>>(zx, dtb, alg, dtv, dAv);
            k_cum<<<1024, 256, 0, stream>>>(dAv, Pt, Pc);
            k_ph1<<<1024, 256, 0, stream>>>(xc, dtv, dAv, Dpp, y, Sl);
            k_comb<<<128, 256, 0, stream>>>(Sl, Pc);
            k_ph3<<<1024, 256, 0, stream>>>(Sl, xc, Pt, y);
            k_gate<<<16384, 256, 0, stream>>>(y, zx, nw);
            if (dir) k_swap<<<4096, 256, 0, stream>>>(y_b, lens);
        }

        // out-projections into comb halves (comb aliases dead zx)
        gemm(y_f, false, nullptr, m_Wout + (size_t)(l * 2 + 0) * 512 * 1024, nullptr, comb,
             false, 16384, 512, 1024, 1024, 0, stream);
        gemm(y_b, false, nullptr, m_Wout + (size_t)(l * 2 + 1) * 512 * 1024, nullptr, comb,
             false, 16384, 512, 1024, 1024, 512, stream);
        // block out-projection (outbuf aliases dead xc)
        gemm(comb, false, nullptr, blk_Wo + (size_t)l * 512 * 1024, blk_bo + l * 512, outbuf,
             false, 16384, 512, 1024, 512, 0, stream);
        // residual + layernorm -> h
        k_ln<<<16384, 256, 0, stream>>>(outbuf, h, ln_g + l * 512, ln_b + l * 512);
    }

    // encoder_outputs = h @ W_enc^T + b_enc -> d_out f32 (y_f/y_b dead)
    gemm(h, false, nullptr, W_enc, b_enc, dout, true, 16384, 1024, 512, 1024, 0, stream);

    hipMemsetAsync(pooled, 0, 8 * 1024 * sizeof(float), stream);
    k_pool<<<512, 256, 0, stream>>>(dout, lens, pooled);
    k_adapter<<<16, 256, 0, stream>>>(pooled, W_ad, b_ad, lens, dout + (size_t)16384 * 1024);
}

// Round 5
// 5645.782 us; speedup vs baseline: 3.0044x; 1.0429x over previous
//
#include <hip/hip_runtime.h>
#include <hip/hip_bf16.h>
#include <math.h>

using bf16 = __hip_bfloat16;
typedef __bf16 bf16x8 __attribute__((ext_vector_type(8)));
typedef float f32x4 __attribute__((ext_vector_type(4)));

#define B2F(x) __bfloat162float(x)
#define F2B(x) __float2bfloat16(x)

__device__ inline short f2bs(float x) { bf16 b = F2B(x); return *(short*)&b; }
__device__ inline float bs2f(short x) { bf16 b; *(short*)&b = x; return B2F(b); }

// Problem constants: B=8, L=2048, H=512, D_INNER=1024, NH=16, P=64, N=64
static constexpr int D_PROJ = 2192, CONV_DIM = 1152;
static constexpr int NCHUNK = 8, CLEN = 256;   // 8 chunks x 256 steps

// Workspace layout (bytes). Total ~146.4 MB. y_f/y_b live in d_out (67.1 MB).
static constexpr size_t OFF_H    = 0;                    // 16384x512  bf16  16.8 MB
static constexpr size_t OFF_ZX   = 16777216;             // 16384x2192 bf16  71.8 MB (comb aliases)
static constexpr size_t OFF_XC   = 88604672;             // 16384x1152 bf16  37.7 MB (outbuf aliases)
static constexpr size_t OFF_S    = 126353408;            // 1024x4096  f32   16.8 MB
static constexpr size_t OFF_PT   = 143130624;            // 16384x16   f32    1.0 MB
static constexpr size_t OFF_PC   = 144179200;            // 1024       f32    4 KB
static constexpr size_t OFF_DTV  = 144183296;            // 16384x16   f32    1.0 MB
static constexpr size_t OFF_DAV  = 145231872;            // 16384x16   f32    1.0 MB
static constexpr size_t OFF_GIDX = 146280448;            // 16384      i32
static constexpr size_t OFF_POOL = 146345984;            // 8x1024     f32

// ---------------------------------------------------------------------------
// MFMA bf16 GEMM: C[M,N] = A[M,K] @ W[N,K]^T + bias
// Epilogue stages the C tile through LDS (union over As/Bs) so global writes
// are full 256B row segments -> kills the write-allocate RMW amplification
// (R4 counters: WRITE_SIZE 280MB for a 72MB output).
// ---------------------------------------------------------------------------
template<bool AF32, bool CF32>
__global__ __launch_bounds__(256, 2)
void k_gemm(const void* __restrict__ Ap, const int* __restrict__ gatherIdx,
            const float* __restrict__ W, const float* __restrict__ bias,
            void* __restrict__ Cp, int M, int N, int K, int ldc, int coff)
{
    __shared__ union UU {
        struct { __align__(16) short As[128 * 40]; __align__(16) short Bs[128 * 40]; } ab;
        __align__(16) short Cs2[128 * 136];                 // bf16 epilogue (34.8 KB)
        __align__(16) float Cs4[CF32 ? 128 * 132 : 4];      // f32 epilogue (67.6 KB)
    } u;

    const int tid  = threadIdx.x;
    const int m0   = blockIdx.y * 128;
    const int n0   = blockIdx.x * 128;
    const int wave = tid >> 6, lane = tid & 63;
    const int l15  = lane & 15, quad = lane >> 4;
    const int wm   = (wave & 1) * 64, wn = (wave >> 1) * 64;

    f32x4 acc[4][4];
#pragma unroll
    for (int i = 0; i < 4; ++i)
#pragma unroll
        for (int j = 0; j < 4; ++j) acc[i][j] = f32x4{0.f, 0.f, 0.f, 0.f};

    const int srow = tid >> 2;
    const int scol = (tid & 3) * 8;

    union V8 { int4 i4; short s[8]; };

    for (int k0 = 0; k0 < K; k0 += 32) {
        V8 av[2], bv[2];
#pragma unroll
        for (int it = 0; it < 2; ++it) {
            int r = srow + it * 64;
            long arow = m0 + r;
            if (gatherIdx) arow = gatherIdx[m0 + r];
            if (AF32) {
                const float* ap = (const float*)Ap + arow * (long)K + k0 + scol;
                float4 f0 = *(const float4*)ap;
                float4 f1 = *(const float4*)(ap + 4);
                av[it].s[0] = f2bs(f0.x); av[it].s[1] = f2bs(f0.y);
                av[it].s[2] = f2bs(f0.z); av[it].s[3] = f2bs(f0.w);
                av[it].s[4] = f2bs(f1.x); av[it].s[5] = f2bs(f1.y);
                av[it].s[6] = f2bs(f1.z); av[it].s[7] = f2bs(f1.w);
            } else {
                av[it].i4 = *(const int4*)((const bf16*)Ap + arow * (long)K + k0 + scol);
            }
            int wr = n0 + r;
            if (wr < N) {
                const float* wp = W + (long)wr * K + k0 + scol;
                float4 f0 = *(const float4*)wp;
                float4 f1 = *(const float4*)(wp + 4);
                bv[it].s[0] = f2bs(f0.x); bv[it].s[1] = f2bs(f0.y);
                bv[it].s[2] = f2bs(f0.z); bv[it].s[3] = f2bs(f0.w);
                bv[it].s[4] = f2bs(f1.x); bv[it].s[5] = f2bs(f1.y);
                bv[it].s[6] = f2bs(f1.z); bv[it].s[7] = f2bs(f1.w);
            } else {
                bv[it].i4 = int4{0, 0, 0, 0};
            }
        }
        __syncthreads();
#pragma unroll
        for (int it = 0; it < 2; ++it) {
            int r = srow + it * 64;
            *(int4*)&u.ab.As[r * 40 + scol] = av[it].i4;
            *(int4*)&u.ab.Bs[r * 40 + scol] = bv[it].i4;
        }
        __syncthreads();

        bf16x8 af[4], bfr[4];
#pragma unroll
        for (int i = 0; i < 4; ++i)
            af[i] = *(const bf16x8*)&u.ab.As[(wm + i * 16 + l15) * 40 + quad * 8];
#pragma unroll
        for (int j = 0; j < 4; ++j)
            bfr[j] = *(const bf16x8*)&u.ab.Bs[(wn + j * 16 + l15) * 40 + quad * 8];
#pragma unroll
        for (int i = 0; i < 4; ++i)
#pragma unroll
            for (int j = 0; j < 4; ++j)
                acc[i][j] = __builtin_amdgcn_mfma_f32_16x16x32_bf16(af[i], bfr[j], acc[i][j], 0, 0, 0);
    }

    // ---- epilogue: stage tile in LDS, write coalesced segments
    __syncthreads();   // all waves done reading As/Bs
    if (!CF32) {
#pragma unroll
        for (int j = 0; j < 4; ++j) {
            int lcol = wn + j * 16 + l15;
            int gcol = n0 + lcol;
            float bvv = (bias && gcol < N) ? bias[gcol] : 0.f;
#pragma unroll
            for (int i = 0; i < 4; ++i)
#pragma unroll
                for (int r = 0; r < 4; ++r)
                    u.Cs2[(wm + i * 16 + quad * 4 + r) * 136 + lcol] = f2bs(acc[i][j][r] + bvv);
        }
        __syncthreads();
        for (int i2 = tid; i2 < 2048; i2 += 256) {
            int lrow = i2 >> 4, seg = i2 & 15;
            int col0 = n0 + seg * 8;               // N % 8 == 0 for all bf16 outputs
            if (col0 < N) {
                int4 v = *(int4*)&u.Cs2[lrow * 136 + seg * 8];
                *(int4*)&((bf16*)Cp)[(long)(m0 + lrow) * ldc + coff + col0] = v;
            }
        }
    } else {
#pragma unroll
        for (int j = 0; j < 4; ++j) {
            int lcol = wn + j * 16 + l15;
            int gcol = n0 + lcol;
            float bvv = (bias && gcol < N) ? bias[gcol] : 0.f;
#pragma unroll
            for (int i = 0; i < 4; ++i)
#pragma unroll
                for (int r = 0; r < 4; ++r)
                    u.Cs4[(wm + i * 16 + quad * 4 + r) * 132 + lcol] = acc[i][j][r] + bvv;
        }
        __syncthreads();
        for (int i2 = tid; i2 < 4096; i2 += 256) {
            int lrow = i2 >> 5, seg = i2 & 31;
            int col0 = n0 + seg * 4;               // N % 4 == 0
            if (col0 < N) {
                int4 v = *(int4*)&u.Cs4[lrow * 132 + seg * 4];
                *(int4*)&((float*)Cp)[(long)(m0 + lrow) * ldc + coff + col0] = v;
            }
        }
    }
}

// ---------------------------------------------------------------------------
// flip row map
// ---------------------------------------------------------------------------
__global__ void k_mkidx(const int* __restrict__ lens, int* __restrict__ gidx)
{
    int idx = blockIdx.x * 256 + threadIdx.x;  // 16384
    int b = idx >> 11, t = idx & 2047;
    int len = lens[b];
    gidx[idx] = b * 2048 + ((t < len) ? (len - 1 - t) : t);
}

// ---------------------------------------------------------------------------
// Depthwise causal conv(k=4)+bias+silu: zx[:,1024:2176] -> xc[16384][1152] bf16
// ---------------------------------------------------------------------------
__global__ __launch_bounds__(256)
void k_conv(const bf16* __restrict__ zx, const float* __restrict__ w,
            const float* __restrict__ cb, bf16* __restrict__ xc)
{
    long idx = (long)blockIdx.x * 256 + threadIdx.x;   // 16384*144
    if (idx >= 16384L * 144) return;
    int  c8 = (int)(idx % 144);
    long bt = idx / 144;
    int  t  = (int)(bt & 2047);
    int  c0 = c8 * 8;

    float acc[8];
#pragma unroll
    for (int i = 0; i < 8; ++i) acc[i] = cb[c0 + i];
#pragma unroll
    for (int j = 0; j < 4; ++j) {
        if (t >= 3 - j) {
            bf16x8 v = *(const bf16x8*)&zx[(bt - 3 + j) * (long)D_PROJ + 1024 + c0];
#pragma unroll
            for (int i = 0; i < 8; ++i) acc[i] += w[(c0 + i) * 4 + j] * (float)v[i];
        }
    }
    short out[8];
#pragma unroll
    for (int i = 0; i < 8; ++i) {
        float a = acc[i];
        out[i] = f2bs(a / (1.f + expf(-a)));
    }
    *(int4*)&xc[bt * (long)CONV_DIM + c0] = *(int4*)out;
}

// ---------------------------------------------------------------------------
// dt = softplus(raw + bias); dA = exp(-exp(Alog)*dt). One dir per launch.
// ---------------------------------------------------------------------------
__global__ void k_dt(const bf16* __restrict__ zx, const float* __restrict__ dtb,
                     const float* __restrict__ alog,
                     float* __restrict__ dtv, float* __restrict__ dAv)
{
    int idx = blockIdx.x * 256 + threadIdx.x;   // 16384*16
    int hh = idx & 15;
    long bt = idx >> 4;
    float x  = B2F(zx[bt * (long)D_PROJ + 2176 + hh]) + dtb[hh];
    float sp = (x > 20.f) ? x : log1pf(expf(x));
    dtv[idx] = sp;
    dAv[idx] = expf(-expf(alog[hh]) * sp);
}

// ---------------------------------------------------------------------------
// Inclusive cumprod of dA within each chunk -> Pt; chunk totals -> Pc.
// ---------------------------------------------------------------------------
__global__ __launch_bounds__(256)
void k_cum(const float* __restrict__ dAv, float* __restrict__ Pt,
           float* __restrict__ Pc)
{
    int blk = blockIdx.x;
    int c = blk & 7, h = (blk >> 3) & 15, b = blk >> 7;
    int tid = threadIdx.x;
    int t = c * CLEN + tid;
    long gi = ((long)(b * 2048 + t) << 4) + h;
    float v = dAv[gi];
    __shared__ float sa[256], sb[256];
    sa[tid] = v; __syncthreads();
    float* src = sa; float* dst = sb;
    for (int off = 1; off < 256; off <<= 1) {
        float x = src[tid];
        if (tid >= off) x *= src[tid - off];
        dst[tid] = x;
        __syncthreads();
        float* tp = src; src = dst; dst = tp;
    }
    float incl = src[tid];
    Pt[gi] = incl;
    if (tid == 255) Pc[blk] = incl;
}

// ---------------------------------------------------------------------------
// Phase 1: local scan per chunk (zero init). 32-row tiles -> LDS 24.8 KB
// -> 6 blocks/CU so all 1024 blocks run in one resident pass.
// 256 threads: p=tid>>2 (0..63), ng=tid&3 (16 n each).
// ---------------------------------------------------------------------------
__global__ __launch_bounds__(256)
void k_ph1(const bf16* __restrict__ xc, const float* __restrict__ dtv,
           const float* __restrict__ dAv, const float* __restrict__ Dp,
           bf16* __restrict__ y, float* __restrict__ Sl)
{
    const int blk = blockIdx.x;
    const int c = blk & 7, h = (blk >> 3) & 15, b = blk >> 7;
    const float Dv = Dp[h];

    __shared__ __align__(16) short xs[32][64];
    __shared__ __align__(16) float Bsm[32][64], Csm[32][64];
    __shared__ __align__(16) short ysb[32][64];
    __shared__ float dA_s[32], dt_s[32];

    const int tid = threadIdx.x;
    const int p = tid >> 2, ng = tid & 3;
    float s[16];
#pragma unroll
    for (int i = 0; i < 16; ++i) s[i] = 0.f;
    const long base = (long)b * 2048;
    const int tcs = c * CLEN;
    const int rr = tid >> 3, sg = (tid & 7) * 8;   // staging coords

    for (int tile = 0; tile < 8; ++tile) {
        const int t0 = tcs + tile * 32;
        // ---- stage x (bf16), B/C (bf16 -> f32): one iteration each
        {
            const bf16* row = &xc[(base + t0 + rr) * (long)CONV_DIM];
            *(int4*)&xs[rr][sg] = *(const int4*)&row[h * 64 + sg];
            bf16x8 vB = *(const bf16x8*)&row[1024 + sg];
            bf16x8 vC = *(const bf16x8*)&row[1088 + sg];
#pragma unroll
            for (int j = 0; j < 8; ++j) { Bsm[rr][sg + j] = (float)vB[j]; Csm[rr][sg + j] = (float)vC[j]; }
        }
        if (tid < 32) {
            long gi = ((base + t0 + tid) << 4) + h;
            dA_s[tid] = dAv[gi];
            dt_s[tid] = dtv[gi];
        }
        __syncthreads();

        // ---- 32 sequential steps
#pragma unroll 4
        for (int tt = 0; tt < 32; ++tt) {
            float dA = dA_s[tt], dtt = dt_s[tt];
            float xp = bs2f(xs[tt][p]);
            float tmp = dtt * xp;
            const float4* Bp = (const float4*)&Bsm[tt][ng * 16];
            const float4* Cq = (const float4*)&Csm[tt][ng * 16];
            float ysum = 0.f;
#pragma unroll
            for (int q = 0; q < 4; ++q) {
                float4 Bv = Bp[q], Cv = Cq[q];
                s[q*4+0] = s[q*4+0] * dA + tmp * Bv.x; ysum += s[q*4+0] * Cv.x;
                s[q*4+1] = s[q*4+1] * dA + tmp * Bv.y; ysum += s[q*4+1] * Cv.y;
                s[q*4+2] = s[q*4+2] * dA + tmp * Bv.z; ysum += s[q*4+2] * Cv.z;
                s[q*4+3] = s[q*4+3] * dA + tmp * Bv.w; ysum += s[q*4+3] * Cv.w;
            }
            ysum += __shfl_xor(ysum, 1);
            ysum += __shfl_xor(ysum, 2);
            if (ng == 0) ysb[tt][p] = f2bs(ysum + Dv * xp);
        }
        __syncthreads();

        // ---- write y tile (coalesced int4); no trailing sync needed:
        // next stage writes xs/B/C (disjoint from ysb) and next step loop's
        // ysb writes are fenced by the post-stage sync.
        *(int4*)&y[(base + t0 + rr) * 1024L + h * 64 + sg] = *(int4*)&ysb[rr][sg];
    }

    // final local state
    float* Sp = Sl + (long)blk * 4096 + p * 64 + ng * 16;
#pragma unroll
    for (int q = 0; q < 4; ++q)
        *(float4*)&Sp[q * 4] = float4{s[q*4+0], s[q*4+1], s[q*4+2], s[q*4+3]};
}

// ---------------------------------------------------------------------------
// Phase 2: sequential combine of chunk states. 128 blocks (b*16+h), 256 thr.
// ---------------------------------------------------------------------------
__global__ __launch_bounds__(256)
void k_comb(float* __restrict__ Sl, const float* __restrict__ Pc)
{
    int bh = blockIdx.x;
    int tid = threadIdx.x;
    float run[16];
#pragma unroll
    for (int i = 0; i < 16; ++i) run[i] = 0.f;
    for (int c = 0; c < NCHUNK; ++c) {
        float* ptr = Sl + ((long)(bh * NCHUNK + c)) * 4096 + tid * 16;
        float pc = Pc[bh * NCHUNK + c];
#pragma unroll
        for (int q = 0; q < 4; ++q) {
            float4 v = *(float4*)&ptr[q * 4];
            float4 init = float4{run[q*4+0], run[q*4+1], run[q*4+2], run[q*4+3]};
            run[q*4+0] = v.x + pc * run[q*4+0];
            run[q*4+1] = v.y + pc * run[q*4+1];
            run[q*4+2] = v.z + pc * run[q*4+2];
            run[q*4+3] = v.w + pc * run[q*4+3];
            *(float4*)&ptr[q * 4] = init;
        }
    }
}

// ---------------------------------------------------------------------------
// Phase 3: y[t] += Pt[t] * (C_t · Sinit). Grid 1024, 256 threads.
// ---------------------------------------------------------------------------
__global__ __launch_bounds__(256)
void k_ph3(const float* __restrict__ Sl, const bf16* __restrict__ xc,
           const float* __restrict__ Pt, bf16* __restrict__ y)
{
    const int blk = blockIdx.x;
    const int c = blk & 7, h = (blk >> 3) & 15, b = blk >> 7;
    if (c == 0) return;   // Sinit = 0

    __shared__ __align__(16) float Cs[64][64];
    __shared__ __align__(16) short ysb[64][64];
    __shared__ float Pts[64];

    const int tid = threadIdx.x;
    const int p = tid >> 2, ng = tid & 3;
    const long base = (long)b * 2048;
    const int tcs = c * CLEN;

    float Sv[16];
    const float* Sp = Sl + (long)blk * 4096 + p * 64 + ng * 16;
#pragma unroll
    for (int q = 0; q < 4; ++q) {
        float4 v = *(const float4*)&Sp[q * 4];
        Sv[q*4+0] = v.x; Sv[q*4+1] = v.y; Sv[q*4+2] = v.z; Sv[q*4+3] = v.w;
    }

    for (int tile = 0; tile < 4; ++tile) {
        const int t0 = tcs + tile * 64;
        for (int i = tid; i < 512; i += 256) {
            int r = i >> 3, sg = (i & 7) * 8;
            bf16x8 v = *(const bf16x8*)&xc[(base + t0 + r) * (long)CONV_DIM + 1088 + sg];
#pragma unroll
            for (int j = 0; j < 8; ++j) Cs[r][sg + j] = (float)v[j];
        }
        if (tid < 64) Pts[tid] = Pt[((base + t0 + tid) << 4) + h];
        __syncthreads();

#pragma unroll 4
        for (int tt = 0; tt < 64; ++tt) {
            const float4* Cq = (const float4*)&Cs[tt][ng * 16];
            float dot = 0.f;
#pragma unroll
            for (int q = 0; q < 4; ++q) {
                float4 Cv = Cq[q];
                dot += Sv[q*4+0] * Cv.x + Sv[q*4+1] * Cv.y
                     + Sv[q*4+2] * Cv.z + Sv[q*4+3] * Cv.w;
            }
            dot += __shfl_xor(dot, 1);
            dot += __shfl_xor(dot, 2);
            if (ng == 0) ysb[tt][p] = f2bs(Pts[tt] * dot);
        }
        __syncthreads();

        // RMW y tile
        for (int i = tid; i < 1024; i += 256) {
            int r = i >> 4, c4 = (i & 15) * 4;
            bf16* yp = &y[(base + t0 + r) * 1024L + h * 64 + c4];
            ushort4 old = *(ushort4*)yp;
            short* corr = &ysb[r][c4];
            ushort4 nw;
            nw.x = (unsigned short)f2bs(bs2f((short)old.x) + bs2f(corr[0]));
            nw.y = (unsigned short)f2bs(bs2f((short)old.y) + bs2f(corr[1]));
            nw.z = (unsigned short)f2bs(bs2f((short)old.z) + bs2f(corr[2]));
            nw.w = (unsigned short)f2bs(bs2f((short)old.w) + bs2f(corr[3]));
            *(ushort4*)yp = nw;
        }
        __syncthreads();
    }
}

// ---------------------------------------------------------------------------
// Gate (y *= silu(z)) + RMSNorm * norm_w, in-place on y.
// ---------------------------------------------------------------------------
__global__ __launch_bounds__(256)
void k_gate(bf16* __restrict__ yp, const bf16* __restrict__ zxp,
            const float* __restrict__ nw)
{
    long bt = blockIdx.x;
    bf16* y = yp + bt * 1024;
    const bf16* z = zxp + bt * (long)D_PROJ;
    int tid = threadIdx.x;
    ushort4 zv = *(const ushort4*)&z[tid * 4];
    ushort4 yv = *(const ushort4*)&y[tid * 4];
    float g[4], ss = 0.f;
    {
        float zz0 = bs2f((short)zv.x), zz1 = bs2f((short)zv.y);
        float zz2 = bs2f((short)zv.z), zz3 = bs2f((short)zv.w);
        float yy0 = bs2f((short)yv.x), yy1 = bs2f((short)yv.y);
        float yy2 = bs2f((short)yv.z), yy3 = bs2f((short)yv.w);
        g[0] = yy0 * (zz0 / (1.f + expf(-zz0)));
        g[1] = yy1 * (zz1 / (1.f + expf(-zz1)));
        g[2] = yy2 * (zz2 / (1.f + expf(-zz2)));
        g[3] = yy3 * (zz3 / (1.f + expf(-zz3)));
        ss = g[0]*g[0] + g[1]*g[1] + g[2]*g[2] + g[3]*g[3];
    }
#pragma unroll
    for (int o = 1; o < 64; o <<= 1) ss += __shfl_xor(ss, o);
    __shared__ float red[4];
    if ((tid & 63) == 0) red[tid >> 6] = ss;
    __syncthreads();
    float tot = red[0] + red[1] + red[2] + red[3];
    float sc = rsqrtf(tot * (1.f / 1024.f) + 1e-5f);
    const float* w = nw + tid * 4;
    ushort4 ov;
    ov.x = (unsigned short)f2bs(g[0] * sc * w[0]);
    ov.y = (unsigned short)f2bs(g[1] * sc * w[1]);
    ov.z = (unsigned short)f2bs(g[2] * sc * w[2]);
    ov.w = (unsigned short)f2bs(g[3] * sc * w[3]);
    *(ushort4*)&y[tid * 4] = ov;
}

// in-place flip via swaps: rows of 1024 bf16 (128 int4)
__global__ void k_swap(bf16* __restrict__ buf, const int* __restrict__ lens)
{
    int idx = blockIdx.x * 256 + threadIdx.x;
    int v = idx & 127;
    int r = idx >> 7;
    int b = r >> 10, t = r & 1023;
    int len = lens[b];
    int t2 = len - 1 - t;
    if (t < len && t < t2) {
        int4* p = (int4*)buf;
        long i1 = ((long)b * 2048 + t)  * 128 + v;
        long i2 = ((long)b * 2048 + t2) * 128 + v;
        int4 a = p[i1], c = p[i2];
        p[i1] = c; p[i2] = a;
    }
}

// LayerNorm(out + h) * g + b -> h (in place)
__global__ __launch_bounds__(256)
void k_ln(const bf16* __restrict__ outb, bf16* __restrict__ h,
          const float* __restrict__ g, const float* __restrict__ bb)
{
    long r = (long)blockIdx.x * 512;
    int tid = threadIdx.x;
    float v0 = B2F(outb[r + tid])       + B2F(h[r + tid]);
    float v1 = B2F(outb[r + tid + 256]) + B2F(h[r + tid + 256]);
    __shared__ float red[4], red2[4];
    float s = v0 + v1;
#pragma unroll
    for (int o = 1; o < 64; o <<= 1) s += __shfl_xor(s, o);
    if ((tid & 63) == 0) red[tid >> 6] = s;
    __syncthreads();
    float mu = (red[0] + red[1] + red[2] + red[3]) * (1.f / 512.f);
    float d0 = v0 - mu, d1 = v1 - mu;
    float q = d0 * d0 + d1 * d1;
#pragma unroll
    for (int o = 1; o < 64; o <<= 1) q += __shfl_xor(q, o);
    if ((tid & 63) == 0) red2[tid >> 6] = q;
    __syncthreads();
    float var = (red2[0] + red2[1] + red2[2] + red2[3]) * (1.f / 512.f);
    float rs = rsqrtf(var + 1e-5f);
    h[r + tid]       = F2B(d0 * rs * g[tid]       + bb[tid]);
    h[r + tid + 256] = F2B(d1 * rs * g[tid + 256] + bb[tid + 256]);
}

// masked-sum pooling partials
__global__ void k_pool(const float* __restrict__ enc, const int* __restrict__ lens,
                       float* __restrict__ pooled)
{
    int bid = blockIdx.x;
    int b = bid >> 6;
    int cg = (bid >> 4) & 3, tc = bid & 15;
    int c = cg * 256 + threadIdx.x;
    int len = lens[b];
    float s = 0.f;
    int tend = tc * 128 + 128;
    for (int t = tc * 128; t < tend; ++t)
        if (t < len) s += enc[((long)b * 2048 + t) * 1024 + c];
    atomicAdd(&pooled[b * 1024 + c], s);
}

// encoder_hidden = tanh(pooled/len @ W_ad^T + b_ad)
__global__ void k_adapter(const float* __restrict__ pooled, const float* __restrict__ Wad,
                          const float* __restrict__ bad, const int* __restrict__ lens,
                          float* __restrict__ outh)
{
    int idx = blockIdx.x * 256 + threadIdx.x;
    int b = idx >> 9, j = idx & 511;
    const float* wrow = Wad + (long)j * 1024;
    const float* prow = pooled + b * 1024;
    float acc = 0.f;
    for (int k = 0; k < 1024; ++k) acc += prow[k] * wrow[k];
    int li = lens[b]; if (li < 1) li = 1;
    acc = acc / (float)li + bad[j];
    outh[idx] = tanhf(acc);
}

// ---------------------------------------------------------------------------
static void gemm(const void* A, bool af32, const int* gather, const float* W,
                 const float* bias, void* C, bool cf32,
                 int M, int N, int K, int ldc, int coff, hipStream_t s)
{
    dim3 grid((N + 127) / 128, M / 128);
    if (af32) {
        if (cf32) k_gemm<true,  true ><<<grid, 256, 0, s>>>(A, gather, W, bias, C, M, N, K, ldc, coff);
        else      k_gemm<true,  false><<<grid, 256, 0, s>>>(A, gather, W, bias, C, M, N, K, ldc, coff);
    } else {
        if (cf32) k_gemm<false, true ><<<grid, 256, 0, s>>>(A, gather, W, bias, C, M, N, K, ldc, coff);
        else      k_gemm<false, false><<<grid, 256, 0, s>>>(A, gather, W, bias, C, M, N, K, ldc, coff);
    }
}

extern "C" void kernel_launch(void* const* d_in, const int* in_sizes, int n_in,
                              void* d_out, int out_size, void* d_ws, size_t ws_size,
                              hipStream_t stream)
{
    const int*   tok    = (const int*)d_in[0];
    const int*   lens   = (const int*)d_in[1];
    const float* emb    = (const float*)d_in[2];
    const float* W_inp  = (const float*)d_in[3];
    const float* b_inp  = (const float*)d_in[4];
    const float* m_Win  = (const float*)d_in[5];
    const float* m_convw= (const float*)d_in[6];
    const float* m_convb= (const float*)d_in[7];
    const float* m_dtb  = (const float*)d_in[8];
    const float* m_Alog = (const float*)d_in[9];
    const float* m_D    = (const float*)d_in[10];
    const float* m_norm = (const float*)d_in[11];
    const float* m_Wout = (const float*)d_in[12];
    const float* blk_Wo = (const float*)d_in[13];
    const float* blk_bo = (const float*)d_in[14];
    const float* ln_g   = (const float*)d_in[15];
    const float* ln_b   = (const float*)d_in[16];
    const float* W_enc  = (const float*)d_in[17];
    const float* b_enc  = (const float*)d_in[18];
    const float* W_ad   = (const float*)d_in[19];
    const float* b_ad   = (const float*)d_in[20];

    char* ws = (char*)d_ws;
    bf16*  h      = (bf16*)(ws + OFF_H);
    bf16*  zx     = (bf16*)(ws + OFF_ZX);
    bf16*  xc     = (bf16*)(ws + OFF_XC);
    float* Sl     = (float*)(ws + OFF_S);
    float* Pt     = (float*)(ws + OFF_PT);
    float* Pc     = (float*)(ws + OFF_PC);
    float* dtv    = (float*)(ws + OFF_DTV);
    float* dAv    = (float*)(ws + OFF_DAV);
    int*   gidx   = (int*)(ws + OFF_GIDX);
    float* pooled = (float*)(ws + OFF_POOL);

    float* dout   = (float*)d_out;
    bf16*  y_f    = (bf16*)d_out;                        // 33.55 MB
    bf16*  y_b    = (bf16*)d_out + (size_t)16384 * 1024; // next 33.55 MB
    bf16*  comb   = (bf16*)(ws + OFF_ZX);                // alias zx (dead after gates)
    bf16*  outbuf = (bf16*)(ws + OFF_XC);                // alias xc (dead after ph3 bwd)

    k_mkidx<<<64, 256, 0, stream>>>(lens, gidx);

    // h = emb[tok] @ W_inp^T + b_inp
    gemm(emb, true, tok, W_inp, b_inp, h, false, 16384, 512, 512, 512, 0, stream);

    for (int l = 0; l < 4; ++l) {
        for (int dir = 0; dir < 2; ++dir) {
            const float* Wi = m_Win  + (size_t)(l * 2 + dir) * D_PROJ * 512;
            const float* cw = m_convw + (size_t)(l * 2 + dir) * CONV_DIM * 4;
            const float* cbp= m_convb + (size_t)(l * 2 + dir) * CONV_DIM;
            const float* dtb= m_dtb  + l * 32 + dir * 16;
            const float* alg= m_Alog + l * 32 + dir * 16;
            const float* Dpp= m_D    + l * 32 + dir * 16;
            const float* nw = m_norm + (size_t)(l * 2 + dir) * 1024;
            bf16* y = dir ? y_b : y_f;

            gemm(h, false, dir ? gidx : nullptr, Wi, nullptr, zx, false,
                 16384, D_PROJ, 512, D_PROJ, 0, stream);
            k_conv<<<9216, 256, 0, stream>>>(zx, cw, cbp, xc);
            k_dt<<<1024, 256, 0, stream>>>(zx, dtb, alg, dtv, dAv);
            k_cum<<<1024, 256, 0, stream>>>(dAv, Pt, Pc);
            k_ph1<<<1024, 256, 0, stream>>>(xc, dtv, dAv, Dpp, y, Sl);
            k_comb<<<128, 256, 0, stream>>>(Sl, Pc);
            k_ph3<<<1024, 256, 0, stream>>>(Sl, xc, Pt, y);
            k_gate<<<16384, 256, 0, stream>>>(y, zx, nw);
            if (dir) k_swap<<<4096, 256, 0, stream>>>(y_b, lens);
        }

        // out-projections into comb halves (comb aliases dead zx)
        gemm(y_f, false, nullptr, m_Wout + (size_t)(l * 2 + 0) * 512 * 1024, nullptr, comb,
             false, 16384, 512, 1024, 1024, 0, stream);
        gemm(y_b, false, nullptr, m_Wout + (size_t)(l * 2 + 1) * 512 * 1024, nullptr, comb,
             false, 16384, 512, 1024, 1024, 512, stream);
        // block out-projection (outbuf aliases dead xc)
        gemm(comb, false, nullptr, blk_Wo + (size_t)l * 512 * 1024, blk_bo + l * 512, outbuf,
             false, 16384, 512, 1024, 512, 0, stream);
        // residual + layernorm -> h
        k_ln<<<16384, 256, 0, stream>>>(outbuf, h, ln_g + l * 512, ln_b + l * 512);
    }

    // encoder_outputs = h @ W_enc^T + b_enc -> d_out f32 (y_f/y_b dead)
    gemm(h, false, nullptr, W_enc, b_enc, dout, true, 16384, 1024, 512, 1024, 0, stream);

    hipMemsetAsync(pooled, 0, 8 * 1024 * sizeof(float), stream);
    k_pool<<<512, 256, 0, stream>>>(dout, lens, pooled);
    k_adapter<<<16, 256, 0, stream>>>(pooled, W_ad, b_ad, lens, dout + (size_t)16384 * 1024);
}